// Round 6
// baseline (352.310 us; speedup 1.0000x reference)
//
#include <hip/hip_runtime.h>
#include <math.h>

#define B_ 16384
#define NP 6
#define CT 288          // compute tiles per p (16 rows each)
#define ZT 512          // zero blocks per p (32 rows each)
#define BPP 800         // CT+ZT
#define PERIOD 25       // 9 compute + 16 zero per period

typedef short v8s __attribute__((ext_vector_type(8)));
typedef float v4f __attribute__((ext_vector_type(4)));

// LDS ushort offsets (1-wave blocks): X1 [16][104], X2 [16][104]
#define X1_O 0
#define X2_O 1664
#define SM_SH 3328

__device__ __forceinline__ float gelu_f(float x) {
    return 0.5f * x * (1.0f + erff(x * 0.7071067811865476f));
}

__device__ __forceinline__ unsigned short f2bf(float f) {
    union { float f; unsigned u; } x; x.f = f;
    unsigned r = x.u + 0x7FFFu + ((x.u >> 16) & 1u);
    return (unsigned short)(r >> 16);
}

// ---------------- kernel 0: weights -> bf16, transposed [col][k] ----------------
__global__ __launch_bounds__(256) void k_prep(
    const float* __restrict__ hw1, const float* __restrict__ gw1,
    const float* __restrict__ hw2, const float* __restrict__ hw3,
    unsigned short* __restrict__ w1t, unsigned short* __restrict__ w2t,
    unsigned short* __restrict__ w3t)
{
    const int T1 = NP * 65536, T2 = NP * 9216, T3 = NP * 49152;
    for (int i = blockIdx.x * 256 + threadIdx.x; i < T1 + T2 + T3; i += gridDim.x * 256) {
        if (i < T1) {
            int p = i >> 16, rem = i & 65535, c = rem >> 9, k = rem & 511;
            float v = (c < 96) ? hw1[p * 49152 + k * 96 + c] : gw1[p * 16384 + k * 32 + (c - 96)];
            w1t[i] = f2bf(v);
        } else if (i < T1 + T2) {
            int j = i - T1, p = j / 9216, r2 = j % 9216, c = r2 / 96, k = r2 % 96;
            w2t[j] = f2bf(hw2[p * 9216 + k * 96 + c]);
        } else {
            int j = i - T1 - T2, p = j / 49152, r3 = j % 49152, c = r3 / 96, k = r3 % 96;
            w3t[j] = f2bf(hw3[p * 49152 + k * 512 + c]);
        }
    }
}

// ---------------- kernel 1: counts + compacted lists + needs bitmap ----------------
__global__ __launch_bounds__(256) void k_count(
    const int* __restrict__ mask, int* __restrict__ counts,
    int* __restrict__ lists, unsigned long long* __restrict__ nb)
{
    int p   = blockIdx.x >> 3;
    int seg = blockIdx.x & 7;
    int src = p >> 1;                        // 0,0,1,1,2,2
    int tgt = (0x102021 >> (p * 4)) & 0xF;   // 1,2,0,2,0,1
    int t = threadIdx.x;
    int lane = t & 63;
    for (int it = 0; it < 8; ++it) {
        int b = seg * 2048 + it * 256 + t;
        int needs = (mask[b * 3 + src] != 0) && (mask[b * 3 + tgt] == 0);
        unsigned long long bal = __ballot(needs);
        int total = __popcll(bal);
        int base = 0;
        if (lane == 0) {
            nb[p * 256 + (b >> 6)] = bal;
            if (total) base = atomicAdd(&counts[p], total);
        }
        base = __shfl(base, 0, 64);
        if (needs) {
            int prefix = __popcll(bal & ((1ull << lane) - 1ull));
            lists[p * B_ + base + prefix] = b;
        }
    }
}

// ---------------- kernel 2: fused MFMA MLP (1-wave blocks) + interleaved zero-fill ----------------
__global__ __launch_bounds__(64) void k_main(
    const float* __restrict__ mus, const float* __restrict__ logvars,
    const unsigned short* __restrict__ w1t, const unsigned short* __restrict__ w2t,
    const unsigned short* __restrict__ w3t,
    const float* __restrict__ hb1, const float* __restrict__ hg1, const float* __restrict__ hbe1,
    const float* __restrict__ hb2, const float* __restrict__ hg2, const float* __restrict__ hbe2,
    const float* __restrict__ hb3,
    const float* __restrict__ gb1, const float* __restrict__ gg1, const float* __restrict__ gbe1,
    const float* __restrict__ gw2, const float* __restrict__ gb2,
    const int* __restrict__ counts, const int* __restrict__ lists,
    const unsigned long long* __restrict__ nb,
    float* __restrict__ out0, float* __restrict__ out1, float* __restrict__ out2)
{
    int bid = blockIdx.x;
    int p   = bid / BPP;
    int r   = bid % BPP;
    int t   = threadIdx.x;           // 0..63
    int g   = t >> 4, q = t & 15;
    int period = r / PERIOD, pos = r % PERIOD;

    if (pos >= 9) {
        // ---------------- zero block: 32 rows ----------------
        int z = period * 16 + (pos - 9);                 // 0..511
        unsigned long long wbits = nb[p * 256 + (z >> 1)];
        int sh = (z & 1) * 32;
        size_t rowbase = ((size_t)p * B_ + (size_t)z * 32) * 256;
        float4 zero = make_float4(0.f, 0.f, 0.f, 0.f);
        for (int rr = 0; rr < 32; ++rr) {
            if (!((wbits >> (sh + rr)) & 1ull)) {
                *(float4*)(out0 + rowbase + (size_t)rr * 256 + t * 4) = zero;
                *(float4*)(out1 + rowbase + (size_t)rr * 256 + t * 4) = zero;
            }
        }
        if (t < 32 && !((wbits >> (sh + t)) & 1ull)) out2[p * B_ + z * 32 + t] = 0.f;
        return;
    }
    int tile = period * 9 + pos;                          // 0..287
    int cnt  = counts[p];

    __shared__ int s_rows[16];
    __shared__ __align__(16) unsigned short sm[SM_SH];

    const float* Ab = mus     + (size_t)(p >> 1) * B_ * 256;
    const float* Lb = logvars + (size_t)(p >> 1) * B_ * 256;
    const unsigned short* w1p = w1t + (size_t)p * 65536;
    const unsigned short* w2p = w2t + (size_t)p * 9216;
    const unsigned short* w3p = w3t + (size_t)p * 49152;
    float gb2p = gb2[p];

    for (int start = tile * 16; start < cnt; start += CT * 16) {
        int nr = min(16, cnt - start);
        __syncthreads();
        if (t < 16) s_rows[t] = lists[p * B_ + start + min(t, nr - 1)];
        __syncthreads();
        int myrow = s_rows[q];

        // ============ phase 1: acc1[8] = rows(16x512) @ [hw1|gw1](512x128), no LDS, no barriers ============
        v4f acc1[8];
#pragma unroll
        for (int n = 0; n < 8; ++n) acc1[n] = (v4f){0.f, 0.f, 0.f, 0.f};

        const float* amu = Ab + (size_t)myrow * 256 + 8 * g;
        const float* alv = Lb + (size_t)myrow * 256 + 8 * g;
        const unsigned short* bp1 = w1p + q * 512 + 8 * g;

#pragma unroll
        for (int kt = 0; kt < 16; ++kt) {
            const float* ap = (kt < 8) ? (amu + kt * 32) : (alv + (kt - 8) * 32);
            float4 f0 = *(const float4*)ap;
            float4 f1 = *(const float4*)(ap + 4);
            v8s a;
            a[0] = (short)f2bf(f0.x); a[1] = (short)f2bf(f0.y);
            a[2] = (short)f2bf(f0.z); a[3] = (short)f2bf(f0.w);
            a[4] = (short)f2bf(f1.x); a[5] = (short)f2bf(f1.y);
            a[6] = (short)f2bf(f1.z); a[7] = (short)f2bf(f1.w);
            const unsigned short* bp = bp1 + kt * 32;
#pragma unroll
            for (int n = 0; n < 8; ++n) {
                v8s b = *(const v8s*)(bp + n * (16 * 512));
                acc1[n] = __builtin_amdgcn_mfma_f32_16x16x32_bf16(a, b, acc1[n], 0, 0, 0);
            }
        }

        // ====== LN1 + gelu (f32, 16-lane shuffles); gate branch fused ======
        {
            float vb[8][4];
#pragma unroll
            for (int n = 0; n < 8; ++n) {
                float bias = (n < 6) ? hb1[p * 96 + n * 16 + q] : gb1[p * 32 + (n - 6) * 16 + q];
#pragma unroll
                for (int j = 0; j < 4; ++j) vb[n][j] = acc1[n][j] + bias;
            }
            float mean[4], rs[4];
#pragma unroll
            for (int j = 0; j < 4; ++j) {
                float hs = vb[0][j] + vb[1][j] + vb[2][j] + vb[3][j] + vb[4][j] + vb[5][j];
                hs += __shfl_xor(hs, 1, 16); hs += __shfl_xor(hs, 2, 16);
                hs += __shfl_xor(hs, 4, 16); hs += __shfl_xor(hs, 8, 16);
                float mn = hs * (1.f / 96.f);
                float sq = 0.f;
#pragma unroll
                for (int n = 0; n < 6; ++n) { float d = vb[n][j] - mn; sq += d * d; }
                sq += __shfl_xor(sq, 1, 16); sq += __shfl_xor(sq, 2, 16);
                sq += __shfl_xor(sq, 4, 16); sq += __shfl_xor(sq, 8, 16);
                mean[j] = mn; rs[j] = rsqrtf(sq * (1.f / 96.f) + 1e-5f);
            }
#pragma unroll
            for (int n = 0; n < 6; ++n) {
                int c = n * 16 + q;
                float ga_ = hg1[p * 96 + c], be_ = hbe1[p * 96 + c];
#pragma unroll
                for (int j = 0; j < 4; ++j) {
                    float x = gelu_f((vb[n][j] - mean[j]) * rs[j] * ga_ + be_);
                    sm[X1_O + (4 * g + j) * 104 + c] = f2bf(x);
                }
            }
            // gate: 32 cols = frags n=6,7
            float g1a = gg1[p * 32 + q],      b1a = gbe1[p * 32 + q],      w2a = gw2[p * 32 + q];
            float g1b = gg1[p * 32 + 16 + q], b1b = gbe1[p * 32 + 16 + q], w2b = gw2[p * 32 + 16 + q];
#pragma unroll
            for (int j = 0; j < 4; ++j) {
                float s = vb[6][j] + vb[7][j];
                s += __shfl_xor(s, 1, 16); s += __shfl_xor(s, 2, 16);
                s += __shfl_xor(s, 4, 16); s += __shfl_xor(s, 8, 16);
                float mg = s * (1.f / 32.f);
                float d6 = vb[6][j] - mg, d7 = vb[7][j] - mg;
                float sq = d6 * d6 + d7 * d7;
                sq += __shfl_xor(sq, 1, 16); sq += __shfl_xor(sq, 2, 16);
                sq += __shfl_xor(sq, 4, 16); sq += __shfl_xor(sq, 8, 16);
                float rg = rsqrtf(sq * (1.f / 32.f) + 1e-5f);
                float gv = gelu_f(d6 * rg * g1a + b1a) * w2a + gelu_f(d7 * rg * g1b + b1b) * w2b;
                gv += __shfl_xor(gv, 1, 16); gv += __shfl_xor(gv, 2, 16);
                gv += __shfl_xor(gv, 4, 16); gv += __shfl_xor(gv, 8, 16);
                int rr = 4 * g + j;
                if (q == 0 && rr < nr)
                    out2[p * B_ + s_rows[rr]] = 1.f / (1.f + expf(-(gv + gb2p)));
            }
        }
        __syncthreads();   // X1 visible (1-wave: compiles to waitcnt)

        // ============ phase 2: acc2[6] = X1(16x96) @ W2(96x96), B direct from L2 ============
        v4f acc2[6];
#pragma unroll
        for (int n = 0; n < 6; ++n) acc2[n] = (v4f){0.f, 0.f, 0.f, 0.f};
#pragma unroll
        for (int kit = 0; kit < 3; ++kit) {
            v8s a = *(const v8s*)(sm + X1_O + q * 104 + kit * 32 + g * 8);
            const unsigned short* bp = w2p + q * 96 + kit * 32 + 8 * g;
#pragma unroll
            for (int n = 0; n < 6; ++n) {
                v8s b = *(const v8s*)(bp + n * (16 * 96));
                acc2[n] = __builtin_amdgcn_mfma_f32_16x16x32_bf16(a, b, acc2[n], 0, 0, 0);
            }
        }

        // ====== LN2 + gelu -> X2 (bf16) ======
        {
            float vc[6][4];
#pragma unroll
            for (int n = 0; n < 6; ++n) {
                float bias = hb2[p * 96 + n * 16 + q];
#pragma unroll
                for (int j = 0; j < 4; ++j) vc[n][j] = acc2[n][j] + bias;
            }
            float mean[4], rs[4];
#pragma unroll
            for (int j = 0; j < 4; ++j) {
                float hs = vc[0][j] + vc[1][j] + vc[2][j] + vc[3][j] + vc[4][j] + vc[5][j];
                hs += __shfl_xor(hs, 1, 16); hs += __shfl_xor(hs, 2, 16);
                hs += __shfl_xor(hs, 4, 16); hs += __shfl_xor(hs, 8, 16);
                float mn = hs * (1.f / 96.f);
                float sq = 0.f;
#pragma unroll
                for (int n = 0; n < 6; ++n) { float d = vc[n][j] - mn; sq += d * d; }
                sq += __shfl_xor(sq, 1, 16); sq += __shfl_xor(sq, 2, 16);
                sq += __shfl_xor(sq, 4, 16); sq += __shfl_xor(sq, 8, 16);
                mean[j] = mn; rs[j] = rsqrtf(sq * (1.f / 96.f) + 1e-5f);
            }
#pragma unroll
            for (int n = 0; n < 6; ++n) {
                int c = n * 16 + q;
                float ga_ = hg2[p * 96 + c], be_ = hbe2[p * 96 + c];
#pragma unroll
                for (int j = 0; j < 4; ++j) {
                    float x = gelu_f((vc[n][j] - mean[j]) * rs[j] * ga_ + be_);
                    sm[X2_O + (4 * g + j) * 104 + c] = f2bf(x);
                }
            }
        }
        __syncthreads();   // X2 visible

        // ============ phase 3: out(16x512) = X2(16x96) @ W3(96x512), 4 panels, B direct ============
#pragma unroll
        for (int pc = 0; pc < 4; ++pc) {
            v4f acc3[8];
#pragma unroll
            for (int n = 0; n < 8; ++n) acc3[n] = (v4f){0.f, 0.f, 0.f, 0.f};
#pragma unroll
            for (int kit = 0; kit < 3; ++kit) {
                v8s a = *(const v8s*)(sm + X2_O + q * 104 + kit * 32 + g * 8);
                const unsigned short* bp = w3p + (pc * 128 + q) * 96 + kit * 32 + 8 * g;
#pragma unroll
                for (int n = 0; n < 8; ++n) {
                    v8s b = *(const v8s*)(bp + n * (16 * 96));
                    acc3[n] = __builtin_amdgcn_mfma_f32_16x16x32_bf16(a, b, acc3[n], 0, 0, 0);
                }
            }
#pragma unroll
            for (int n = 0; n < 8; ++n) {
                int c = pc * 128 + n * 16 + q;
                float bias = hb3[p * 512 + c];
#pragma unroll
                for (int j = 0; j < 4; ++j) {
                    int rr = 4 * g + j;
                    if (rr < nr) {
                        float o = acc3[n][j] + bias;
                        size_t base = ((size_t)(p * B_ + s_rows[rr])) * 256;
                        if (pc < 2) out0[base + c] = o;
                        else        out1[base + c - 256] = fminf(fmaxf(o, -6.f), 2.f);
                    }
                }
            }
        }
    }
}

extern "C" void kernel_launch(void* const* d_in, const int* in_sizes, int n_in,
                              void* d_out, int out_size, void* d_ws, size_t ws_size,
                              hipStream_t stream)
{
    (void)in_sizes; (void)n_in; (void)out_size; (void)ws_size;

    const float* mus     = (const float*)d_in[0];
    const float* logvars = (const float*)d_in[1];
    const int*   mask    = (const int*)d_in[2];   // numpy bool -> int32 per harness
    const float* hw1  = (const float*)d_in[3];
    const float* hb1  = (const float*)d_in[4];
    const float* hg1  = (const float*)d_in[5];
    const float* hbe1 = (const float*)d_in[6];
    const float* hw2  = (const float*)d_in[7];
    const float* hb2  = (const float*)d_in[8];
    const float* hg2  = (const float*)d_in[9];
    const float* hbe2 = (const float*)d_in[10];
    const float* hw3  = (const float*)d_in[11];
    const float* hb3  = (const float*)d_in[12];
    const float* gw1  = (const float*)d_in[13];
    const float* gb1  = (const float*)d_in[14];
    const float* gg1  = (const float*)d_in[15];
    const float* gbe1 = (const float*)d_in[16];
    const float* gw2  = (const float*)d_in[17];
    const float* gb2  = (const float*)d_in[18];

    float* out0 = (float*)d_out;
    float* out1 = out0 + (size_t)NP * B_ * 256;
    float* out2 = out1 + (size_t)NP * B_ * 256;

    int* counts = (int*)d_ws;                                    // 16 ints
    int* lists  = counts + 16;                                   // NP*B_ ints
    unsigned short* w1t = (unsigned short*)(lists + NP * B_);    // NP*65536
    unsigned short* w2t = w1t + (size_t)NP * 65536;              // NP*9216
    unsigned short* w3t = w2t + (size_t)NP * 9216;               // NP*49152
    unsigned long long* nbm = (unsigned long long*)(w3t + (size_t)NP * 49152);  // NP*256

    hipMemsetAsync(d_ws, 0, 64, stream);
    k_count<<<dim3(NP * 8), dim3(256), 0, stream>>>(mask, counts, lists, nbm);
    k_prep<<<dim3(512), dim3(256), 0, stream>>>(hw1, gw1, hw2, hw3, w1t, w2t, w3t);
    k_main<<<dim3(NP * BPP), dim3(64), 0, stream>>>(
        mus, logvars, w1t, w2t, w3t,
        hb1, hg1, hbe1, hb2, hg2, hbe2, hb3,
        gb1, gg1, gbe1, gw2, gb2,
        counts, lists, nbm, out0, out1, out2);
}

// Round 7
// 122.931 us; speedup vs baseline: 2.8659x; 2.8659x over previous
//
#include <hip/hip_runtime.h>
#include <math.h>

#define B_ 16384
#define NP 6
#define CTB 72      // compute blocks per p (64 live rows each)
#define ZB  128     // zero blocks per p (128 rows each)
#define PPB 200     // blocks per p
#define PERIOD 25   // 9 compute + 16 zero

typedef short v8s __attribute__((ext_vector_type(8)));
typedef short v4s __attribute__((ext_vector_type(4)));
typedef float v4f __attribute__((ext_vector_type(4)));

__device__ __forceinline__ float gelu_f(float x) {
    return 0.5f * x * (1.0f + erff(x * 0.7071067811865476f));
}
__device__ __forceinline__ unsigned short f2bf(float f) {
    union { float f; unsigned u; } x; x.f = f;
    unsigned r = x.u + 0x7FFFu + ((x.u >> 16) & 1u);
    return (unsigned short)(r >> 16);
}

// ---------------- kernel 0: weights -> bf16, transposed [col][k] ----------------
__global__ __launch_bounds__(256) void k_prep(
    const float* __restrict__ hw1, const float* __restrict__ gw1,
    const float* __restrict__ hw2, const float* __restrict__ hw3,
    unsigned short* __restrict__ w1t, unsigned short* __restrict__ w2t,
    unsigned short* __restrict__ w3t)
{
    const int T1 = NP * 65536, T2 = NP * 9216, T3 = NP * 49152;
    for (int i = blockIdx.x * 256 + threadIdx.x; i < T1 + T2 + T3; i += gridDim.x * 256) {
        if (i < T1) {
            int p = i >> 16, rem = i & 65535, c = rem >> 9, k = rem & 511;
            float v = (c < 96) ? hw1[p * 49152 + k * 96 + c] : gw1[p * 16384 + k * 32 + (c - 96)];
            w1t[i] = f2bf(v);
        } else if (i < T1 + T2) {
            int j = i - T1, p = j / 9216, r2 = j % 9216, c = r2 / 96, k = r2 % 96;
            w2t[j] = f2bf(hw2[p * 9216 + k * 96 + c]);
        } else {
            int j = i - T1 - T2, p = j / 49152, r3 = j % 49152, c = r3 / 96, k = r3 % 96;
            w3t[j] = f2bf(hw3[p * 49152 + k * 512 + c]);
        }
    }
}

// ---------------- kernel 1: counts + compacted lists + needs bitmap ----------------
__global__ __launch_bounds__(256) void k_count(
    const int* __restrict__ mask, int* __restrict__ counts,
    int* __restrict__ lists, unsigned long long* __restrict__ nb)
{
    int p   = blockIdx.x >> 3;
    int seg = blockIdx.x & 7;
    int src = p >> 1;                        // 0,0,1,1,2,2
    int tgt = (0x102021 >> (p * 4)) & 0xF;   // 1,2,0,2,0,1
    int t = threadIdx.x;
    int lane = t & 63;
    for (int it = 0; it < 8; ++it) {
        int b = seg * 2048 + it * 256 + t;
        int needs = (mask[b * 3 + src] != 0) && (mask[b * 3 + tgt] == 0);
        unsigned long long bal = __ballot(needs);
        int total = __popcll(bal);
        int base = 0;
        if (lane == 0) {
            nb[p * 256 + (b >> 6)] = bal;
            if (total) base = atomicAdd(&counts[p], total);
        }
        base = __shfl(base, 0, 64);
        if (needs) {
            int prefix = __popcll(bal & ((1ull << lane) - 1ull));
            lists[p * B_ + base + prefix] = b;
        }
    }
}

// ---------------- kernel 2: fused MFMA MLP (4-wave) + interleaved zero-fill ----------------
__global__ __launch_bounds__(256, 3) void k_main(
    const float* __restrict__ mus, const float* __restrict__ logvars,
    const unsigned short* __restrict__ w1t, const unsigned short* __restrict__ w2t,
    const unsigned short* __restrict__ w3t,
    const float* __restrict__ hb1, const float* __restrict__ hg1, const float* __restrict__ hbe1,
    const float* __restrict__ hb2, const float* __restrict__ hg2, const float* __restrict__ hbe2,
    const float* __restrict__ hb3,
    const float* __restrict__ gb1, const float* __restrict__ gg1, const float* __restrict__ gbe1,
    const float* __restrict__ gw2, const float* __restrict__ gb2,
    const int* __restrict__ counts, const int* __restrict__ lists,
    const unsigned long long* __restrict__ nb,
    float* __restrict__ out0, float* __restrict__ out1, float* __restrict__ out2)
{
    int bid = blockIdx.x;
    int p = bid / PPB;
    int r = bid % PPB;
    int t = threadIdx.x;
    int w = t >> 6, l = t & 63, g = l >> 4, q = l & 15;
    int period = r / PERIOD, pos = r % PERIOD;

    if (pos >= 9) {
        // ---------------- zero block: 128 rows ----------------
        int zb = period * 16 + (pos - 9);                // 0..127
        int row0 = zb * 128 + w * 32;
        unsigned long long wd = nb[p * 256 + (row0 >> 6)];
        int sh = row0 & 63;
        size_t rowbase = ((size_t)p * B_ + row0) * 256;
        float4 zero = make_float4(0.f, 0.f, 0.f, 0.f);
        for (int rr = 0; rr < 32; ++rr) {
            if (!((wd >> (sh + rr)) & 1ull)) {
                *(float4*)(out0 + rowbase + (size_t)rr * 256 + l * 4) = zero;
                *(float4*)(out1 + rowbase + (size_t)rr * 256 + l * 4) = zero;
            }
        }
        if (t < 128) {
            int row = zb * 128 + t;
            if (!((nb[p * 256 + (row >> 6)] >> (row & 63)) & 1ull))
                out2[p * B_ + row] = 0.f;
        }
        return;
    }
    int ctile = period * 9 + pos;                        // 0..71
    int cnt = counts[p];

    __shared__ int s_rows[64];
    __shared__ __align__(16) unsigned short smW[18432];  // 2 x [128 cols][72]
    __shared__ __align__(16) unsigned short smX[6656];   // 4 waves x [16 rows][104]

    const float* Ab = mus     + (size_t)(p >> 1) * B_ * 256;
    const float* Lb = logvars + (size_t)(p >> 1) * B_ * 256;
    const unsigned short* w1p = w1t + (size_t)p * 65536;
    const unsigned short* w2p = w2t + (size_t)p * 9216;
    const unsigned short* w3p = w3t + (size_t)p * 49152;
    unsigned short* mX = smX + w * 1664;
    float gb2p = gb2[p];

    int scol = t >> 1, shalf = t & 1;    // W1 staging role

    for (int s0 = ctile * 64; s0 < cnt; s0 += CTB * 64) {
        __syncthreads();
        if (t < 64) s_rows[t] = lists[p * B_ + min(s0 + t, cnt - 1)];
        __syncthreads();

        int nrw = min(16, cnt - (s0 + w * 16));          // may be <= 0
        bool active = nrw > 0;
        int myrow = s_rows[w * 16 + q];
        const float* Arow = Ab + (size_t)myrow * 256;
        const float* Lrow = Lb + (size_t)myrow * 256;

        // ============ phase 1: acc1[8] = (W1T frag) x (h rows), K=512 ============
        v4f acc1[8];
#pragma unroll
        for (int n = 0; n < 8; ++n) acc1[n] = (v4f){0.f, 0.f, 0.f, 0.f};

        {   // prologue: stage chunk 0
            const unsigned short* src = w1p + scol * 512 + shalf * 32;
            unsigned short* dst = smW + scol * 72 + shalf * 32;
#pragma unroll
            for (int j = 0; j < 4; ++j) *(v8s*)(dst + j * 8) = *(const v8s*)(src + j * 8);
        }
        __syncthreads();

#pragma unroll 1
        for (int kt = 0; kt < 8; ++kt) {
            const unsigned short* cur = smW + (kt & 1) * 9216;
            if (kt < 7) {   // stage next chunk into other buffer
                const unsigned short* src = w1p + scol * 512 + (kt + 1) * 64 + shalf * 32;
                unsigned short* dst = smW + ((kt + 1) & 1) * 9216 + scol * 72 + shalf * 32;
#pragma unroll
                for (int j = 0; j < 4; ++j) *(v8s*)(dst + j * 8) = *(const v8s*)(src + j * 8);
            }
            if (active) {
                const float* ap = ((kt < 4) ? Arow : Lrow) + (kt & 3) * 64;
#pragma unroll
                for (int kit = 0; kit < 2; ++kit) {
                    const float* a8 = ap + kit * 32 + g * 8;
                    float4 f0 = *(const float4*)a8;
                    float4 f1 = *(const float4*)(a8 + 4);
                    v8s a;
                    a[0] = (short)f2bf(f0.x); a[1] = (short)f2bf(f0.y);
                    a[2] = (short)f2bf(f0.z); a[3] = (short)f2bf(f0.w);
                    a[4] = (short)f2bf(f1.x); a[5] = (short)f2bf(f1.y);
                    a[6] = (short)f2bf(f1.z); a[7] = (short)f2bf(f1.w);
#pragma unroll
                    for (int n = 0; n < 8; ++n) {
                        v8s b = *(const v8s*)(cur + (n * 16 + q) * 72 + kit * 32 + g * 8);
                        acc1[n] = __builtin_amdgcn_mfma_f32_16x16x32_bf16(b, a, acc1[n], 0, 0, 0);
                    }
                }
            }
            __syncthreads();
        }

        // ====== LN1 + gelu; lane (g,q) holds row q, cols {n*16+4g+j} ======
        if (active) {
            float vb[8][4];
#pragma unroll
            for (int n = 0; n < 8; ++n) {
                float4 bb = (n < 6) ? *(const float4*)(hb1 + p * 96 + n * 16 + 4 * g)
                                    : *(const float4*)(gb1 + p * 32 + (n - 6) * 16 + 4 * g);
                vb[n][0] = acc1[n][0] + bb.x; vb[n][1] = acc1[n][1] + bb.y;
                vb[n][2] = acc1[n][2] + bb.z; vb[n][3] = acc1[n][3] + bb.w;
            }
            float hs = 0.f;
#pragma unroll
            for (int n = 0; n < 6; ++n)
#pragma unroll
                for (int j = 0; j < 4; ++j) hs += vb[n][j];
            hs += __shfl_xor(hs, 16, 64); hs += __shfl_xor(hs, 32, 64);
            float mean = hs * (1.f / 96.f);
            float sq = 0.f;
#pragma unroll
            for (int n = 0; n < 6; ++n)
#pragma unroll
                for (int j = 0; j < 4; ++j) { float d = vb[n][j] - mean; sq += d * d; }
            sq += __shfl_xor(sq, 16, 64); sq += __shfl_xor(sq, 32, 64);
            float rs = rsqrtf(sq * (1.f / 96.f) + 1e-5f);
#pragma unroll
            for (int n = 0; n < 6; ++n) {
                float4 ga = *(const float4*)(hg1  + p * 96 + n * 16 + 4 * g);
                float4 be = *(const float4*)(hbe1 + p * 96 + n * 16 + 4 * g);
                v4s xo;
                xo[0] = (short)f2bf(gelu_f((vb[n][0] - mean) * rs * ga.x + be.x));
                xo[1] = (short)f2bf(gelu_f((vb[n][1] - mean) * rs * ga.y + be.y));
                xo[2] = (short)f2bf(gelu_f((vb[n][2] - mean) * rs * ga.z + be.z));
                xo[3] = (short)f2bf(gelu_f((vb[n][3] - mean) * rs * ga.w + be.w));
                *(v4s*)(mX + q * 104 + n * 16 + 4 * g) = xo;
            }
            // gate branch (cols 96..127 = frags n=6,7)
            float gs = 0.f;
#pragma unroll
            for (int n = 6; n < 8; ++n)
#pragma unroll
                for (int j = 0; j < 4; ++j) gs += vb[n][j];
            gs += __shfl_xor(gs, 16, 64); gs += __shfl_xor(gs, 32, 64);
            float mg = gs * (1.f / 32.f);
            float gq = 0.f;
#pragma unroll
            for (int n = 6; n < 8; ++n)
#pragma unroll
                for (int j = 0; j < 4; ++j) { float d = vb[n][j] - mg; gq += d * d; }
            gq += __shfl_xor(gq, 16, 64); gq += __shfl_xor(gq, 32, 64);
            float rg = rsqrtf(gq * (1.f / 32.f) + 1e-5f);
            float gv = 0.f;
#pragma unroll
            for (int n = 6; n < 8; ++n) {
                int cg = (n - 6) * 16 + 4 * g;
                float4 ga = *(const float4*)(gg1  + p * 32 + cg);
                float4 be = *(const float4*)(gbe1 + p * 32 + cg);
                float4 w2 = *(const float4*)(gw2  + p * 32 + cg);
                gv += gelu_f((vb[n][0] - mg) * rg * ga.x + be.x) * w2.x;
                gv += gelu_f((vb[n][1] - mg) * rg * ga.y + be.y) * w2.y;
                gv += gelu_f((vb[n][2] - mg) * rg * ga.z + be.z) * w2.z;
                gv += gelu_f((vb[n][3] - mg) * rg * ga.w + be.w) * w2.w;
            }
            gv += __shfl_xor(gv, 16, 64); gv += __shfl_xor(gv, 32, 64);
            if (g == 0 && q < nrw)
                out2[p * B_ + myrow] = 1.f / (1.f + expf(-(gv + gb2p)));
        }
        __syncthreads();

        // ============ phase 2: acc2[6] = (W2T frag) x (X1 rows), K=96 ============
        if (active) {
            v4f acc2[6];
#pragma unroll
            for (int n = 0; n < 6; ++n) acc2[n] = (v4f){0.f, 0.f, 0.f, 0.f};
#pragma unroll
            for (int kit = 0; kit < 3; ++kit) {
                v8s xa = *(const v8s*)(mX + q * 104 + kit * 32 + g * 8);
#pragma unroll
                for (int n = 0; n < 6; ++n) {
                    v8s wb = *(const v8s*)(w2p + (n * 16 + q) * 96 + kit * 32 + g * 8);
                    acc2[n] = __builtin_amdgcn_mfma_f32_16x16x32_bf16(wb, xa, acc2[n], 0, 0, 0);
                }
            }
            // LN2 + gelu -> X2 (same buffer, after reads complete)
            float vc[6][4];
#pragma unroll
            for (int n = 0; n < 6; ++n) {
                float4 bb = *(const float4*)(hb2 + p * 96 + n * 16 + 4 * g);
                vc[n][0] = acc2[n][0] + bb.x; vc[n][1] = acc2[n][1] + bb.y;
                vc[n][2] = acc2[n][2] + bb.z; vc[n][3] = acc2[n][3] + bb.w;
            }
            float hs = 0.f;
#pragma unroll
            for (int n = 0; n < 6; ++n)
#pragma unroll
                for (int j = 0; j < 4; ++j) hs += vc[n][j];
            hs += __shfl_xor(hs, 16, 64); hs += __shfl_xor(hs, 32, 64);
            float mean = hs * (1.f / 96.f);
            float sq = 0.f;
#pragma unroll
            for (int n = 0; n < 6; ++n)
#pragma unroll
                for (int j = 0; j < 4; ++j) { float d = vc[n][j] - mean; sq += d * d; }
            sq += __shfl_xor(sq, 16, 64); sq += __shfl_xor(sq, 32, 64);
            float rs = rsqrtf(sq * (1.f / 96.f) + 1e-5f);
#pragma unroll
            for (int n = 0; n < 6; ++n) {
                float4 ga = *(const float4*)(hg2  + p * 96 + n * 16 + 4 * g);
                float4 be = *(const float4*)(hbe2 + p * 96 + n * 16 + 4 * g);
                v4s xo;
                xo[0] = (short)f2bf(gelu_f((vc[n][0] - mean) * rs * ga.x + be.x));
                xo[1] = (short)f2bf(gelu_f((vc[n][1] - mean) * rs * ga.y + be.y));
                xo[2] = (short)f2bf(gelu_f((vc[n][2] - mean) * rs * ga.z + be.z));
                xo[3] = (short)f2bf(gelu_f((vc[n][3] - mean) * rs * ga.w + be.w));
                *(v4s*)(mX + q * 104 + n * 16 + 4 * g) = xo;
            }
        }
        __syncthreads();

        // ============ phase 3: out rows = (W3T frag) x (X2 rows), float4 stores ============
        if (active) {
            size_t base = ((size_t)(p * B_ + myrow)) * 256;
#pragma unroll 1
            for (int pc = 0; pc < 4; ++pc) {
                v4f acc3[8];
#pragma unroll
                for (int n = 0; n < 8; ++n) acc3[n] = (v4f){0.f, 0.f, 0.f, 0.f};
#pragma unroll
                for (int kit = 0; kit < 3; ++kit) {
                    v8s xa = *(const v8s*)(mX + q * 104 + kit * 32 + g * 8);
#pragma unroll
                    for (int n = 0; n < 8; ++n) {
                        v8s wb = *(const v8s*)(w3p + (size_t)(pc * 128 + n * 16 + q) * 96 + kit * 32 + g * 8);
                        acc3[n] = __builtin_amdgcn_mfma_f32_16x16x32_bf16(wb, xa, acc3[n], 0, 0, 0);
                    }
                }
#pragma unroll
                for (int n = 0; n < 8; ++n) {
                    int c = pc * 128 + n * 16 + 4 * g;
                    float4 bb = *(const float4*)(hb3 + p * 512 + c);
                    if (q < nrw) {
                        float o0 = acc3[n][0] + bb.x, o1 = acc3[n][1] + bb.y;
                        float o2 = acc3[n][2] + bb.z, o3 = acc3[n][3] + bb.w;
                        if (pc < 2) {
                            *(float4*)(out0 + base + c) = make_float4(o0, o1, o2, o3);
                        } else {
                            o0 = fminf(fmaxf(o0, -6.f), 2.f); o1 = fminf(fmaxf(o1, -6.f), 2.f);
                            o2 = fminf(fmaxf(o2, -6.f), 2.f); o3 = fminf(fmaxf(o3, -6.f), 2.f);
                            *(float4*)(out1 + base + c - 256) = make_float4(o0, o1, o2, o3);
                        }
                    }
                }
            }
        }
    }
}

extern "C" void kernel_launch(void* const* d_in, const int* in_sizes, int n_in,
                              void* d_out, int out_size, void* d_ws, size_t ws_size,
                              hipStream_t stream)
{
    (void)in_sizes; (void)n_in; (void)out_size; (void)ws_size;

    const float* mus     = (const float*)d_in[0];
    const float* logvars = (const float*)d_in[1];
    const int*   mask    = (const int*)d_in[2];   // numpy bool -> int32 per harness
    const float* hw1  = (const float*)d_in[3];
    const float* hb1  = (const float*)d_in[4];
    const float* hg1  = (const float*)d_in[5];
    const float* hbe1 = (const float*)d_in[6];
    const float* hw2  = (const float*)d_in[7];
    const float* hb2  = (const float*)d_in[8];
    const float* hg2  = (const float*)d_in[9];
    const float* hbe2 = (const float*)d_in[10];
    const float* hw3  = (const float*)d_in[11];
    const float* hb3  = (const float*)d_in[12];
    const float* gw1  = (const float*)d_in[13];
    const float* gb1  = (const float*)d_in[14];
    const float* gg1  = (const float*)d_in[15];
    const float* gbe1 = (const float*)d_in[16];
    const float* gw2  = (const float*)d_in[17];
    const float* gb2  = (const float*)d_in[18];

    float* out0 = (float*)d_out;
    float* out1 = out0 + (size_t)NP * B_ * 256;
    float* out2 = out1 + (size_t)NP * B_ * 256;

    int* counts = (int*)d_ws;                                    // 16 ints
    int* lists  = counts + 16;                                   // NP*B_ ints
    unsigned short* w1t = (unsigned short*)(lists + NP * B_);    // NP*65536
    unsigned short* w2t = w1t + (size_t)NP * 65536;              // NP*9216
    unsigned short* w3t = w2t + (size_t)NP * 9216;               // NP*49152
    unsigned long long* nbm = (unsigned long long*)(w3t + (size_t)NP * 49152);  // NP*256

    hipMemsetAsync(d_ws, 0, 64, stream);
    k_count<<<dim3(NP * 8), dim3(256), 0, stream>>>(mask, counts, lists, nbm);
    k_prep<<<dim3(512), dim3(256), 0, stream>>>(hw1, gw1, hw2, hw3, w1t, w2t, w3t);
    k_main<<<dim3(NP * PPB), dim3(256), 0, stream>>>(
        mus, logvars, w1t, w2t, w3t,
        hb1, hg1, hbe1, hb2, hg2, hbe2, hb3,
        gb1, gg1, gbe1, gw2, gb2,
        counts, lists, nbm, out0, out1, out2);
}